// Round 2
// baseline (201.634 us; speedup 1.0000x reference)
//
#include <hip/hip_runtime.h>
#include <math.h>

#define T_LEN      24000
#define TS         1600          // samples per time slice
#define NSLICE     15            // 15 * 1600 = 24000
#define W_LEN      81
#define HALF_W     40
#define NK         21
#define MAXORD     10
#define NIMG_TOTAL 1561          // |{k in [-10,10]^3 : |kx|+|ky|+|kz| <= 10}|
#define FS_F       48000.0f
#define C_F        343.0f
#define PI_F       3.14159265358979323846f
#define FOUR_PI_F  12.566370614359172f
#define NEG_SLOPE  0.01f
#define NTHREADS   256

// ---- compile-time table of valid image triples ----
// entry: (order << 15) | (kxi << 10) | (kyi << 5) | kzi   (kxi etc. in [0,21))
struct Table { unsigned int e[NIMG_TOTAL]; };

constexpr Table make_table() {
    Table t{};
    int n = 0;
    for (int kx = 0; kx < NK; ++kx)
        for (int ky = 0; ky < NK; ++ky)
            for (int kz = 0; kz < NK; ++kz) {
                int ax = kx >= MAXORD ? kx - MAXORD : MAXORD - kx;
                int ay = ky >= MAXORD ? ky - MAXORD : MAXORD - ky;
                int az = kz >= MAXORD ? kz - MAXORD : MAXORD - kz;
                int order = ax + ay + az;
                if (order <= MAXORD)
                    t.e[n++] = (unsigned)((order << 15) | (kx << 10) | (ky << 5) | kz);
            }
    return t;
}
__constant__ Table g_tbl = make_table();

__global__ __launch_bounds__(NTHREADS)
void rir_slice_kernel(const float* __restrict__ g_in,
                      const float* __restrict__ W1, const float* __restrict__ b1,
                      const float* __restrict__ W2, const float* __restrict__ b2,
                      const float* __restrict__ W3, const float* __restrict__ b3,
                      float* __restrict__ out_rir, float* __restrict__ out_origin)
{
    __shared__ __align__(16) float rir[TS];          // 6400 B
    __shared__ float2 params[NIMG_TOTAL];            // 12488 B (amp, delay)
    __shared__ float hann[W_LEN];                    // 324 B
    __shared__ float dsq[3 * NK];                    // (img - mic)^2 per axis
    __shared__ float h1[30], h2[20], zb[9], sm_in[22], rms[9];
    __shared__ float beta_pow[MAXORD + 1];
    __shared__ int cnt;

    const int tid = threadIdx.x;
    const int s   = blockIdx.x;          // time slice
    const int b   = blockIdx.y;          // batch row
    const int lo  = s * TS;

    // ---- parallel init (all waves) ----
    #pragma unroll
    for (int i = tid; i < TS; i += NTHREADS) rir[i] = 0.0f;
    if (tid >= 64 && tid < 64 + W_LEN) {
        int j = tid - 64;
        hann[j] = 0.5f * (1.0f - cosf(2.0f * PI_F * (float)j / (float)(W_LEN - 1)));
    }
    if (tid >= 160 && tid <= 160 + MAXORD) beta_pow[tid - 160] = powf(0.9f, (float)(tid - 160));
    if (tid == 192) cnt = 0;

    // ---- wave 0: input row, MLP, geometry (in-wave LDS ordering, no barriers) ----
    if (tid < 64) {
        if (tid < 22) sm_in[tid] = g_in[b * 22 + tid];
        if (tid < 30) {
            float a = b1[tid];
            const float* w = W1 + tid * 22;
            #pragma unroll
            for (int i = 0; i < 22; ++i) a += sm_in[i] * w[i];
            h1[tid] = (a >= 0.0f) ? a : NEG_SLOPE * a;
        }
        if (tid < 20) {
            float a = b2[tid];
            const float* w = W2 + tid * 30;
            #pragma unroll
            for (int i = 0; i < 30; ++i) a += h1[i] * w[i];
            h2[tid] = (a >= 0.0f) ? a : NEG_SLOPE * a;
        }
        if (tid < 9) {
            float a = b3[tid];
            const float* w = W3 + tid * 20;
            #pragma unroll
            for (int i = 0; i < 20; ++i) a += h2[i] * w[i];
            zb[tid] = 1.0f / (1.0f + expf(-a));
        }
        if (tid < 3) {
            float room = zb[tid] * 20.0f;
            rms[tid]     = room;
            rms[3 + tid] = zb[3 + tid] * room;   // mic
            rms[6 + tid] = zb[6 + tid] * room;   // src
        }
        if (tid == 0 && s == 0) {
            float dx = rms[3] - rms[6], dy = rms[4] - rms[7], dz = rms[5] - rms[8];
            out_origin[b] = 40.0f + FS_F * sqrtf(dx * dx + dy * dy + dz * dz) / C_F;
        }
        if (tid < 3 * NK) {
            int a  = tid / NK;
            int kk = (tid - a * NK) - MAXORD;
            float L = rms[a], src = rms[6 + a];
            float img = ((kk & 1) == 0) ? (float)kk * L + src : (float)(kk + 1) * L - src;
            float diff = img - rms[3 + a];
            dsq[tid] = diff * diff;
        }
    }
    __syncthreads();

    // ---- enumerate valid images, keep those whose window touches this slice ----
    const float lof = (float)(lo - HALF_W);
    const float hif = (float)(lo + TS - 1 + HALF_W);
    for (int i = tid; i < NIMG_TOTAL; i += NTHREADS) {
        unsigned e = g_tbl.e[i];
        int kzi = e & 31, kyi = (e >> 5) & 31, kxi = (e >> 10) & 31, order = e >> 15;
        float d = sqrtf(dsq[kxi] + dsq[NK + kyi] + dsq[2 * NK + kzi]);
        float delay = 40.0f + (FS_F * d) / C_F;
        float t0f = floorf(delay);
        if (t0f >= lof && t0f <= hif) {
            float amp = beta_pow[order] / (FOUR_PI_F * fmaxf(d, 0.001f));
            int pos = atomicAdd(&cnt, 1);
            params[pos] = make_float2(amp, delay);
        }
    }
    __syncthreads();

    // ---- scatter windowed-sinc taps into the LDS slice ----
    const int nimg  = cnt;
    const int ntask = nimg * W_LEN;
    for (int task = tid; task < ntask; task += NTHREADS) {
        int img = (int)((unsigned)task / (unsigned)W_LEN);
        int j   = task - img * W_LEN;
        float2 p = params[img];                 // amp, delay
        float t0f  = floorf(p.y);
        float frac = p.y - t0f;
        int   n    = j - HALF_W;
        int   idx  = (int)t0f + n - lo;
        if ((unsigned)idx < (unsigned)TS) {
            float x  = (float)n - frac;
            float sn = __sinf(PI_F * frac);
            float sp = (j & 1) ? sn : -sn;      // sin(pi*(n-frac)) = -(-1)^n sin(pi*frac)
            float sv = (x == 0.0f) ? 1.0f : sp * __builtin_amdgcn_rcpf(PI_F * x);
            atomicAdd(&rir[idx], p.x * sv * hann[j]);
        }
    }
    __syncthreads();

    // ---- coalesced writeback of this slice ----
    float4* out4 = (float4*)(out_rir + (size_t)b * T_LEN + lo);
    float4* rir4 = (float4*)rir;
    #pragma unroll
    for (int i = tid; i < TS / 4; i += NTHREADS) out4[i] = rir4[i];
}

extern "C" void kernel_launch(void* const* d_in, const int* in_sizes, int n_in,
                              void* d_out, int out_size, void* d_ws, size_t ws_size,
                              hipStream_t stream) {
    const float* g_in = (const float*)d_in[0];
    const float* W1   = (const float*)d_in[1];
    const float* b1   = (const float*)d_in[2];
    const float* W2   = (const float*)d_in[3];
    const float* b2   = (const float*)d_in[4];
    const float* W3   = (const float*)d_in[5];
    const float* b3   = (const float*)d_in[6];

    const int B = in_sizes[0] / 22;

    float* out_rir    = (float*)d_out;
    float* out_origin = out_rir + (size_t)B * T_LEN;

    dim3 grid(NSLICE, B);
    rir_slice_kernel<<<grid, NTHREADS, 0, stream>>>(
        g_in, W1, b1, W2, b2, W3, b3, out_rir, out_origin);
}

// Round 3
// 135.723 us; speedup vs baseline: 1.4856x; 1.4856x over previous
//
#include <hip/hip_runtime.h>
#include <math.h>

#define T_LEN      24000
#define TS         1792          // samples per slice = 256 threads * 7
#define NSLICE     14            // 14 * 1792 = 25088 >= 24000 (last slice partial: 704)
#define SPT        7             // samples per thread
#define W_LEN      81
#define HALF_W     40
#define NK         21
#define MAXORD     10
#define NIMG_TOTAL 1561          // |{k in [-10,10]^3 : |kx|+|ky|+|kz| <= 10}|
#define FS_F       48000.0f
#define C_F        343.0f
#define PI_F       3.14159265358979323846f
#define FOUR_PI_F  12.566370614359172f
#define NEG_SLOPE  0.01f
#define NTHREADS   256

// ---- compile-time table of valid image triples ----
// entry: (order << 15) | (kxi << 10) | (kyi << 5) | kzi
struct Table { unsigned int e[NIMG_TOTAL]; };

constexpr Table make_table() {
    Table t{};
    int n = 0;
    for (int kx = 0; kx < NK; ++kx)
        for (int ky = 0; ky < NK; ++ky)
            for (int kz = 0; kz < NK; ++kz) {
                int ax = kx >= MAXORD ? kx - MAXORD : MAXORD - kx;
                int ay = ky >= MAXORD ? ky - MAXORD : MAXORD - ky;
                int az = kz >= MAXORD ? kz - MAXORD : MAXORD - kz;
                int order = ax + ay + az;
                if (order <= MAXORD)
                    t.e[n++] = (unsigned)((order << 15) | (kx << 10) | (ky << 5) | kz);
            }
    return t;
}
__constant__ Table g_tbl = make_table();

__global__ __launch_bounds__(NTHREADS)
void rir_gather_kernel(const float* __restrict__ g_in,
                       const float* __restrict__ W1, const float* __restrict__ b1,
                       const float* __restrict__ W2, const float* __restrict__ b2,
                       const float* __restrict__ W3, const float* __restrict__ b3,
                       float* __restrict__ out_rir, float* __restrict__ out_origin)
{
    __shared__ float2 params[NIMG_TOTAL];            // (amp, delay) 12488 B
    __shared__ __align__(16) float rir[TS];          // 7168 B (no init needed: each slot written once)
    __shared__ float hann[W_LEN];
    __shared__ float dsq[3 * NK];                    // (img - mic)^2 per axis
    __shared__ float h1[30], h2[20], zb[9], sm_in[22], rms[9];
    __shared__ float beta_pow[MAXORD + 1];
    __shared__ int cnt;

    const int tid = threadIdx.x;
    const int s   = blockIdx.x;          // time slice
    const int b   = blockIdx.y;          // batch row
    const int lo  = s * TS;

    // ---- parallel init ----
    if (tid >= 64 && tid < 64 + W_LEN) {
        int j = tid - 64;
        hann[j] = 0.5f * (1.0f - cosf(2.0f * PI_F * (float)j / (float)(W_LEN - 1)));
    }
    if (tid >= 160 && tid <= 160 + MAXORD) beta_pow[tid - 160] = powf(0.9f, (float)(tid - 160));
    if (tid == 192) cnt = 0;

    // ---- wave 0: input row, MLP, geometry (in-wave LDS ordering) ----
    if (tid < 64) {
        if (tid < 22) sm_in[tid] = g_in[b * 22 + tid];
        if (tid < 30) {
            float a = b1[tid];
            const float* w = W1 + tid * 22;
            #pragma unroll
            for (int i = 0; i < 22; ++i) a += sm_in[i] * w[i];
            h1[tid] = (a >= 0.0f) ? a : NEG_SLOPE * a;
        }
        if (tid < 20) {
            float a = b2[tid];
            const float* w = W2 + tid * 30;
            #pragma unroll
            for (int i = 0; i < 30; ++i) a += h1[i] * w[i];
            h2[tid] = (a >= 0.0f) ? a : NEG_SLOPE * a;
        }
        if (tid < 9) {
            float a = b3[tid];
            const float* w = W3 + tid * 20;
            #pragma unroll
            for (int i = 0; i < 20; ++i) a += h2[i] * w[i];
            zb[tid] = 1.0f / (1.0f + expf(-a));
        }
        if (tid < 3) {
            float room = zb[tid] * 20.0f;
            rms[tid]     = room;
            rms[3 + tid] = zb[3 + tid] * room;   // mic
            rms[6 + tid] = zb[6 + tid] * room;   // src
        }
        if (tid == 0 && s == 0) {
            float dx = rms[3] - rms[6], dy = rms[4] - rms[7], dz = rms[5] - rms[8];
            out_origin[b] = 40.0f + FS_F * sqrtf(dx * dx + dy * dy + dz * dz) / C_F;
        }
        if (tid < 3 * NK) {
            int a  = tid / NK;
            int kk = (tid - a * NK) - MAXORD;
            float L = rms[a], src = rms[6 + a];
            float img = ((kk & 1) == 0) ? (float)kk * L + src : (float)(kk + 1) * L - src;
            float diff = img - rms[3 + a];
            dsq[tid] = diff * diff;
        }
    }
    __syncthreads();

    // ---- enumerate valid images whose window can touch this slice ----
    const float lof = (float)(lo - HALF_W - 1);
    const float hif = (float)(lo + TS - 1 + HALF_W + 1);
    for (int i = tid; i < NIMG_TOTAL; i += NTHREADS) {
        unsigned e = g_tbl.e[i];
        int kzi = e & 31, kyi = (e >> 5) & 31, kxi = (e >> 10) & 31, order = e >> 15;
        float d = sqrtf(dsq[kxi] + dsq[NK + kyi] + dsq[2 * NK + kzi]);
        float delay = 40.0f + (FS_F * d) / C_F;
        float t0f = floorf(delay);
        if (t0f >= lof && t0f <= hif) {
            float amp = beta_pow[order] / (FOUR_PI_F * fmaxf(d, 0.001f));
            int pos = atomicAdd(&cnt, 1);
            params[pos] = make_float2(amp, delay);
        }
    }
    __syncthreads();

    // ---- gather: each thread owns SPT consecutive samples in registers ----
    const int base = lo + tid * SPT;     // first global sample owned by this thread
    float acc[SPT];
    #pragma unroll
    for (int k = 0; k < SPT; ++k) acc[k] = 0.0f;

    const int nimg = cnt;
    for (int i = 0; i < nimg; ++i) {
        float2 p = params[i];            // uniform-address LDS broadcast read
        float t0f  = floorf(p.y);
        int   rel  = (int)t0f - base;    // local coord of t0; tap n = k - rel
        if (rel < -HALF_W || rel > HALF_W + SPT - 1) continue;
        float frac = p.y - t0f;
        float sn   = __sinf(PI_F * frac);
        #pragma unroll
        for (int k = 0; k < SPT; ++k) {
            int n = k - rel;             // t - t0
            if ((unsigned)(n + HALF_W) < (unsigned)W_LEN) {
                float x  = (float)n - frac;              // t - delay
                float sp = (n & 1) ? sn : -sn;           // sin(pi*x) = -(-1)^n sin(pi*frac)
                float sv = (x == 0.0f) ? 1.0f
                                       : sp * __builtin_amdgcn_rcpf(PI_F * x);
                acc[k] += p.x * sv * hann[n + HALF_W];
            }
        }
    }

    // ---- stage to LDS (exclusive ownership, no atomics), coalesced writeback ----
    #pragma unroll
    for (int k = 0; k < SPT; ++k) rir[tid * SPT + k] = acc[k];
    __syncthreads();

    const int nout = min(TS, T_LEN - lo);          // 1792, or 704 for the last slice
    float4* out4 = (float4*)(out_rir + (size_t)b * T_LEN + lo);
    float4* rir4 = (float4*)rir;
    for (int i = tid; i < nout / 4; i += NTHREADS) out4[i] = rir4[i];
}

extern "C" void kernel_launch(void* const* d_in, const int* in_sizes, int n_in,
                              void* d_out, int out_size, void* d_ws, size_t ws_size,
                              hipStream_t stream) {
    const float* g_in = (const float*)d_in[0];
    const float* W1   = (const float*)d_in[1];
    const float* b1   = (const float*)d_in[2];
    const float* W2   = (const float*)d_in[3];
    const float* b2   = (const float*)d_in[4];
    const float* W3   = (const float*)d_in[5];
    const float* b3   = (const float*)d_in[6];

    const int B = in_sizes[0] / 22;

    float* out_rir    = (float*)d_out;
    float* out_origin = out_rir + (size_t)B * T_LEN;

    dim3 grid(NSLICE, B);
    rir_gather_kernel<<<grid, NTHREADS, 0, stream>>>(
        g_in, W1, b1, W2, b2, W3, b3, out_rir, out_origin);
}